// Round 6
// baseline (133.133 us; speedup 1.0000x reference)
//
#include <hip/hip_runtime.h>

#define RES    256
#define NPIX   (RES * RES)
#define NTRI   1000
#define NTRIP  1024          // padded triangle count (always-skip padding)
#define EPSF   1e-8f
#define CPT    12            // coef dwords per triangle
#define TC     8             // triangle chunks in rasterize
#define TPC    (NTRIP / TC)  // 128, multiple of 8
#define LOG2E2 2.8853900817779268f   // 2*log2(e)

// coef layout (12 dwords/tri): a0,b0,c0,a1,b1,c1,a2,b2,c2, ik, mn*ik, pad
//   edge_i(px,py) = a*px + b*py + c ;  x2 = fma(s, ik, -mn*ik) ; tanh = 1-2*rcp(1+exp2(x2))
// bbox array (1 dword/tri, contiguous): bx0 | bx1<<8 | by0<<16 | by1<<24
//   empty/off-screen/padding = 0x00FF00FF (bx0=255,bx1=0) -> skips for every strip

// ---------------------------------------------------------------------------
// Kernel A: one block per (batch, padded-triangle). Project, coefficients,
// bbox, min/max of score over bbox pixels. Also grid-stride zeroes `out`
// (replaces a separate memset dispatch; rasterize runs after us in-stream).
// ---------------------------------------------------------------------------
__global__ __launch_bounds__(256) void tri_setup(
    const float* __restrict__ meshes, const float* __restrict__ Km,
    const int* __restrict__ midx, const float* __restrict__ cams,
    float* __restrict__ coef, unsigned int* __restrict__ bbox,
    float* __restrict__ out, int nout)
{
    const int blk = blockIdx.x;
    const int b = blk >> 10;
    const int t = blk & (NTRIP - 1);

    // zero output image
    {
        const int g = blk * 256 + threadIdx.x;
        if (g < nout) out[g] = 0.0f;
    }

    float* r = coef + (((size_t)b << 10) + t) * CPT;
    unsigned int* bb = bbox + ((size_t)b << 10) + t;

    if (t >= NTRI) {               // padding triangle: always-skip
        if (threadIdx.x == 0) {
            *bb = 0x00FF00FFu;
#pragma unroll
            for (int k = 0; k < CPT; ++k) r[k] = 0.0f;
        }
        return;
    }

    const float* cam = cams + b * 12;
    float M[12];
#pragma unroll
    for (int i = 0; i < 3; ++i) {
        const float k0 = Km[i*3+0], k1 = Km[i*3+1], k2 = Km[i*3+2];
#pragma unroll
        for (int j = 0; j < 4; ++j)
            M[i*4+j] = k0*cam[j] + k1*cam[4+j] + k2*cam[8+j];
    }
    const int m = midx[b];
    const float* tv = meshes + ((size_t)m * NTRI + t) * 9;
    float vx[3], vy[3];
#pragma unroll
    for (int v = 0; v < 3; ++v) {
        const float X = tv[v*3+0], Y = tv[v*3+1], Z = tv[v*3+2];
        const float w = M[8]*X + M[9]*Y + M[10]*Z + M[11] + EPSF;
        vx[v] = (M[0]*X + M[1]*Y + M[2]*Z + M[3]) / w;
        vy[v] = (M[4]*X + M[5]*Y + M[6]*Z + M[7]) / w;
    }

    const float e0x = vx[1]-vx[0], e0y = vy[1]-vy[0];
    const float e1x = vx[2]-vx[1], e1y = vy[2]-vy[1];
    const float e2x = vx[0]-vx[2], e2y = vy[0]-vy[2];
    const float N = e0x*e2y - e0y*e2x + EPSF;

    const float a0 = N*e0y, b0 = -N*e0x, c0 = N*(e0x*vy[0] - e0y*vx[0]);
    const float a1 = N*e1y, b1 = -N*e1x, c1 = N*(e1x*vy[1] - e1y*vx[1]);
    const float a2 = N*e2y, b2 = -N*e2x, c2 = N*(e2x*vy[2] - e2y*vx[2]);

    float mnx = fminf(fminf(vx[0],vx[1]),vx[2]);
    float mxx = fmaxf(fmaxf(vx[0],vx[1]),vx[2]);
    float mny = fminf(fminf(vy[0],vy[1]),vy[2]);
    float mxy = fmaxf(fmaxf(vy[0],vy[1]),vy[2]);
    mnx = fmaxf(fminf(mnx, 1e6f), -1e6f);  mxx = fmaxf(fminf(mxx, 1e6f), -1e6f);
    mny = fmaxf(fminf(mny, 1e6f), -1e6f);  mxy = fmaxf(fminf(mxy, 1e6f), -1e6f);
    const int bx0 = max(0,     (int)floorf(mnx) - 1);
    const int bx1 = min(RES-1, (int)ceilf (mxx) + 1);
    const int by0 = max(0,     (int)floorf(mny) - 1);
    const int by1 = min(RES-1, (int)ceilf (mxy) + 1);
    const bool empty = (bx0 > bx1) || (by0 > by1);

    float mn = INFINITY, mx = -INFINITY;
    if (!empty) {
        const int h = by1 - by0 + 1;
        int sh = 0;
        while ((1 << sh) < h) ++sh;
        const int hp = 1 << sh;
        const int area = (bx1 - bx0 + 1) << sh;
        for (int p = threadIdx.x; p < area; p += 256) {
            const int x = bx0 + (p >> sh);
            const int y = by0 + (p & (hp - 1));
            if (y <= by1) {
                const float fx = (float)x, fy = (float)y;
                const float t1 = fmaxf(fmaf(a0, fx, fmaf(b0, fy, c0)), 0.0f);
                const float t2 = fmaxf(fmaf(a1, fx, fmaf(b1, fy, c1)), 0.0f);
                const float t3 = fmaxf(fmaf(a2, fx, fmaf(b2, fy, c2)), 0.0f);
                const float s = t1 * t2 * t3;
                mn = fminf(mn, s);
                mx = fmaxf(mx, s);
            }
        }
    }
#pragma unroll
    for (int off = 32; off > 0; off >>= 1) {
        mn = fminf(mn, __shfl_down(mn, off, 64));
        mx = fmaxf(mx, __shfl_down(mx, off, 64));
    }
    __shared__ float smn[4], smx[4];
    const int lane = threadIdx.x & 63, wv = threadIdx.x >> 6;
    if (lane == 0) { smn[wv] = mn; smx[wv] = mx; }
    __syncthreads();
    if (threadIdx.x == 0) {
        mn = fminf(fminf(smn[0], smn[1]), fminf(smn[2], smn[3]));
        mx = fmaxf(fmaxf(smx[0], smx[1]), fmaxf(smx[2], smx[3]));
        if (empty) { mn = 0.0f; mx = 0.0f; }
        const bool fullgrid = (bx0 == 0 && bx1 == RES-1 && by0 == 0 && by1 == RES-1);
        if (!fullgrid) mn = 0.0f;   // some grid pixel strictly outside => s==0 there
        const float ik = LOG2E2 / (mx - mn + EPSF);
        r[0]=a0; r[1]=b0; r[2]=c0; r[3]=a1; r[4]=b1; r[5]=c1;
        r[6]=a2; r[7]=b2; r[8]=c2;
        r[9]=ik; r[10]=mn*ik; r[11]=0.0f;
        *bb = empty ? 0x00FF00FFu
                    : ((unsigned)bx0 | ((unsigned)bx1 << 8) |
                       ((unsigned)by0 << 16) | ((unsigned)by1 << 24));
    }
}

// ---------------------------------------------------------------------------
// Kernel B: block = 4 columns x 256 rows (4 px/thread). Grid = batch * 64
// column-strips * TC chunks. Per 8-triangle group: batched scalar bbox loads,
// scalar survival mask, group fast-skip; coef record loaded only on survival.
// ---------------------------------------------------------------------------
__global__ __launch_bounds__(256) void rasterize(
    const float* __restrict__ coef, const unsigned int* __restrict__ bbox,
    float* __restrict__ out)
{
    const int blk  = blockIdx.x;
    const int b    = blk / (64 * TC);
    const int rem  = blk - b * (64 * TC);
    const int tcid = rem >> 6;
    const int xg   = rem & 63;
    const int x0   = xg << 2;

    const float fy  = (float)threadIdx.x;
    const float fx0 = (float)x0;
    const float fx1 = fx0 + 1.0f, fx2 = fx0 + 2.0f, fx3 = fx0 + 3.0f;
    const int wy0 = __builtin_amdgcn_readfirstlane(threadIdx.x);
    const int wy1 = wy0 + 63;

    float acc0 = 0.0f, acc1 = 0.0f, acc2 = 0.0f, acc3 = 0.0f, fcnt = 0.0f;
    const unsigned int* bbp = bbox + ((size_t)b << 10) + tcid * TPC;
    const float* cbase = coef + (((size_t)b << 10) + (size_t)tcid * TPC) * CPT;

    for (int i0 = 0; i0 < TPC; i0 += 8) {
        unsigned int bbs[8];
#pragma unroll
        for (int k = 0; k < 8; ++k) bbs[k] = bbp[i0 + k];
        unsigned int smask = 0;
#pragma unroll
        for (int k = 0; k < 8; ++k) {
            const int tbx0 = bbs[k] & 255, tbx1 = (bbs[k] >> 8) & 255;
            const int tby0 = (bbs[k] >> 16) & 255, tby1 = bbs[k] >> 24;
            const bool hit = !(tbx1 < x0 || tbx0 > x0 + 3 || tby1 < wy0 || tby0 > wy1);
            smask |= (hit ? 1u : 0u) << k;
        }
        if (smask == 0) continue;
#pragma unroll
        for (int k = 0; k < 8; ++k) {
            if (!(smask & (1u << k))) continue;
            const float* r = cbase + (i0 + k) * CPT;
            const float a0 = r[0], b0 = r[1], c0 = r[2];
            const float a1 = r[3], b1 = r[4], c1 = r[5];
            const float a2 = r[6], b2 = r[7], c2 = r[8];
            const float ik = r[9], mnik = r[10];
            const float B0 = fmaf(b0, fy, c0);
            const float B1 = fmaf(b1, fy, c1);
            const float B2 = fmaf(b2, fy, c2);
            {
                const float u1 = fmaxf(fmaf(a0, fx0, B0), 0.0f);
                const float u2 = fmaxf(fmaf(a1, fx0, B1), 0.0f);
                const float u3 = fmaxf(fmaf(a2, fx0, B2), 0.0f);
                const float e  = __builtin_amdgcn_exp2f(fmaf(u1*u2*u3, ik, -mnik));
                acc0 += __builtin_amdgcn_rcpf(1.0f + e);
            }
            {
                const float u1 = fmaxf(fmaf(a0, fx1, B0), 0.0f);
                const float u2 = fmaxf(fmaf(a1, fx1, B1), 0.0f);
                const float u3 = fmaxf(fmaf(a2, fx1, B2), 0.0f);
                const float e  = __builtin_amdgcn_exp2f(fmaf(u1*u2*u3, ik, -mnik));
                acc1 += __builtin_amdgcn_rcpf(1.0f + e);
            }
            {
                const float u1 = fmaxf(fmaf(a0, fx2, B0), 0.0f);
                const float u2 = fmaxf(fmaf(a1, fx2, B1), 0.0f);
                const float u3 = fmaxf(fmaf(a2, fx2, B2), 0.0f);
                const float e  = __builtin_amdgcn_exp2f(fmaf(u1*u2*u3, ik, -mnik));
                acc2 += __builtin_amdgcn_rcpf(1.0f + e);
            }
            {
                const float u1 = fmaxf(fmaf(a0, fx3, B0), 0.0f);
                const float u2 = fmaxf(fmaf(a1, fx3, B1), 0.0f);
                const float u3 = fmaxf(fmaf(a2, fx3, B2), 0.0f);
                const float e  = __builtin_amdgcn_exp2f(fmaf(u1*u2*u3, ik, -mnik));
                acc3 += __builtin_amdgcn_rcpf(1.0f + e);
            }
            fcnt += 1.0f;
        }
    }

    float* o = out + (size_t)b * NPIX + (size_t)x0 * RES + threadIdx.x;
    atomicAdd(o,         fmaf(-2.0f, acc0, fcnt));
    atomicAdd(o + RES,   fmaf(-2.0f, acc1, fcnt));
    atomicAdd(o + 2*RES, fmaf(-2.0f, acc2, fcnt));
    atomicAdd(o + 3*RES, fmaf(-2.0f, acc3, fcnt));
}

extern "C" void kernel_launch(void* const* d_in, const int* in_sizes, int n_in,
                              void* d_out, int out_size, void* d_ws, size_t ws_size,
                              hipStream_t stream)
{
    const float* meshes = (const float*)d_in[0];
    const float* Km     = (const float*)d_in[1];
    const int*   midx   = (const int*)d_in[2];
    const float* cams   = (const float*)d_in[3];
    float* out = (float*)d_out;

    const int batch = in_sizes[3] / 12;     // camera_poses is (B,3,4)

    float* coef = (float*)d_ws;                                   // batch*1024*12 floats
    unsigned int* bbox =
        (unsigned int*)((char*)d_ws + (size_t)batch * NTRIP * CPT * sizeof(float));

    tri_setup<<<dim3(batch * NTRIP), dim3(256), 0, stream>>>(
        meshes, Km, midx, cams, coef, bbox, out, batch * NPIX);
    rasterize<<<dim3(batch * 64 * TC), dim3(256), 0, stream>>>(coef, bbox, out);
}